// Round 1
// baseline (1530.103 us; speedup 1.0000x reference)
//
#include <hip/hip_runtime.h>
#include <math.h>

#define NB 4
#define TT 16
#define NNODE 1000
#define FIN 8
#define EE 8000
#define EP 9000          // E + N self loops
#define HID 64
#define HEADS 4
#define NL 5
#define GG (NB*TT)       // 64 graphs
#define ROWS (GG*NNODE)  // 64000
#define HCOL (HEADS*HID) // 256
#define KGI (NNODE*HID)  // 64000
#define GOUT 192         // 3*HID

// ---------------- edge prep ----------------
__global__ void k_build_edges(const int* __restrict__ eidx, int* __restrict__ src_e,
                              int* __restrict__ dst_e, int* __restrict__ deg, int* __restrict__ fill) {
    int i = blockIdx.x * blockDim.x + threadIdx.x;
    if (i < EP) {
        int s, d;
        if (i < EE) { s = eidx[i]; d = eidx[EE + i]; }
        else { s = i - EE; d = i - EE; }
        src_e[i] = s; dst_e[i] = d;
    }
    if (i < NNODE) { deg[i] = 0; fill[i] = 0; }
}

__global__ void k_csr_count(const int* __restrict__ dst_e, int* __restrict__ deg) {
    int i = blockIdx.x * blockDim.x + threadIdx.x;
    if (i < EP) atomicAdd(&deg[dst_e[i]], 1);
}

__global__ void k_csr_scan(const int* __restrict__ deg, int* __restrict__ rowptr) {
    if (threadIdx.x == 0) {
        int acc = 0;
        rowptr[0] = 0;
        for (int i = 0; i < NNODE; i++) { acc += deg[i]; rowptr[i + 1] = acc; }
    }
}

__global__ void k_csr_fill(const int* __restrict__ dst_e, const int* __restrict__ rowptr,
                           int* __restrict__ fill, int* __restrict__ colidx) {
    int i = blockIdx.x * blockDim.x + threadIdx.x;
    if (i < EP) {
        int d = dst_e[i];
        int pos = atomicAdd(&fill[d], 1);
        colidx[rowptr[d] + pos] = i;
    }
}

// ---------------- input projection ----------------
__global__ void k_input_fc(const float* __restrict__ xseq, const float* __restrict__ W_in,
                           const float* __restrict__ b_in, float* __restrict__ x0) {
    int idx = blockIdx.x * 256 + threadIdx.x;   // ROWS*HID threads
    int r = idx >> 6, c = idx & 63;
    float acc = b_in[c];
    #pragma unroll
    for (int k = 0; k < FIN; k++) acc += xseq[r * FIN + k] * W_in[k * HID + c];
    x0[idx] = acc;
}

// ---------------- GAT: h = x @ W, plus ls/ld attention dots ----------------
__global__ __launch_bounds__(256) void k_gat_h(const float* __restrict__ x, const float* __restrict__ W,
                                               const float* __restrict__ asrc, const float* __restrict__ adst,
                                               float* __restrict__ h, float* __restrict__ ls, float* __restrict__ ld) {
    __shared__ float xs[64 * 65];                 // [node][k], padded
    __shared__ __align__(16) float ws[64 * 64];   // [k][c]
    int r0 = blockIdx.x * 64;
    int head = blockIdx.y;
    int c0 = head * 64;
    int tid = threadIdx.x;
    for (int idx = tid; idx < 4096; idx += 256) {
        int a = idx >> 6, b = idx & 63;
        xs[a * 65 + b] = x[(r0 + a) * HID + b];
        ws[idx] = W[a * HCOL + c0 + b];
    }
    __syncthreads();
    int tx = tid & 15, ty = tid >> 4;
    float acc[4][4] = {};
    for (int k = 0; k < 64; k++) {
        float4 w4 = *reinterpret_cast<const float4*>(&ws[k * 64 + tx * 4]);
        #pragma unroll
        for (int i = 0; i < 4; i++) {
            float xv = xs[(ty * 4 + i) * 65 + k];
            acc[i][0] += xv * w4.x;
            acc[i][1] += xv * w4.y;
            acc[i][2] += xv * w4.z;
            acc[i][3] += xv * w4.w;
        }
    }
    #pragma unroll
    for (int i = 0; i < 4; i++) {
        float4 v = make_float4(acc[i][0], acc[i][1], acc[i][2], acc[i][3]);
        *reinterpret_cast<float4*>(&h[(r0 + ty * 4 + i) * HCOL + c0 + tx * 4]) = v;
    }
    float a0 = asrc[c0 + tx * 4 + 0], a1 = asrc[c0 + tx * 4 + 1];
    float a2 = asrc[c0 + tx * 4 + 2], a3 = asrc[c0 + tx * 4 + 3];
    float d0 = adst[c0 + tx * 4 + 0], d1 = adst[c0 + tx * 4 + 1];
    float d2 = adst[c0 + tx * 4 + 2], d3 = adst[c0 + tx * 4 + 3];
    #pragma unroll
    for (int i = 0; i < 4; i++) {
        float ps = acc[i][0] * a0 + acc[i][1] * a1 + acc[i][2] * a2 + acc[i][3] * a3;
        float pd = acc[i][0] * d0 + acc[i][1] * d1 + acc[i][2] * d2 + acc[i][3] * d3;
        #pragma unroll
        for (int m = 1; m < 16; m <<= 1) {
            ps += __shfl_xor(ps, m, 64);
            pd += __shfl_xor(pd, m, 64);
        }
        if (tx == 0) {
            ls[(r0 + ty * 4 + i) * HEADS + head] = ps;
            ld[(r0 + ty * 4 + i) * HEADS + head] = pd;
        }
    }
}

// ---------------- GAT: softmax over incoming edges + aggregate ----------------
__global__ __launch_bounds__(256) void k_gat_agg(const float* __restrict__ h, const float* __restrict__ ls,
                                                 const float* __restrict__ ld, const int* __restrict__ rowptr,
                                                 const int* __restrict__ colidx, const int* __restrict__ src_e,
                                                 const float* __restrict__ bg, float* __restrict__ xout) {
    int n = blockIdx.x, g = blockIdx.y;
    int tid = threadIdx.x;
    int hd = tid >> 6, lane = tid & 63;
    int base = g * NNODE;
    int rs = rowptr[n], re = rowptr[n + 1];
    float ldv = ld[(base + n) * HEADS + hd];
    // pass 1: max
    float m = -INFINITY;
    for (int idx = rs + lane; idx < re; idx += 64) {
        int s = src_e[colidx[idx]];
        float v = ls[(base + s) * HEADS + hd] + ldv;
        v = v >= 0.f ? v : 0.2f * v;
        m = fmaxf(m, v);
    }
    #pragma unroll
    for (int o = 1; o < 64; o <<= 1) m = fmaxf(m, __shfl_xor(m, o, 64));
    // pass 2: denominator
    float den = 0.f;
    for (int idx = rs + lane; idx < re; idx += 64) {
        int s = src_e[colidx[idx]];
        float v = ls[(base + s) * HEADS + hd] + ldv;
        v = v >= 0.f ? v : 0.2f * v;
        den += expf(v - m);
    }
    #pragma unroll
    for (int o = 1; o < 64; o <<= 1) den += __shfl_xor(den, o, 64);
    float inv = 1.f / (den + 1e-16f);
    // pass 3: aggregate
    float acc = 0.f;
    for (int b = rs; b < re; b += 64) {
        int myidx = b + lane;
        float myalpha = 0.f; int mysrc = 0;
        if (myidx < re) {
            int s = src_e[colidx[myidx]];
            mysrc = s;
            float v = ls[(base + s) * HEADS + hd] + ldv;
            v = v >= 0.f ? v : 0.2f * v;
            myalpha = expf(v - m) * inv;
        }
        int cnt = min(64, re - b);
        for (int j = 0; j < cnt; j++) {
            float a = __shfl(myalpha, j, 64);
            int s = __shfl(mysrc, j, 64);
            acc += a * h[(base + s) * HCOL + hd * HID + lane];
        }
    }
    __shared__ float agg[4][64];
    agg[hd][lane] = acc;
    __syncthreads();
    if (tid < 64) {
        float v = (agg[0][tid] + agg[1][tid] + agg[2][tid] + agg[3][tid]) * 0.25f + bg[tid];
        v = v > 0.f ? v : expm1f(v);
        xout[(base + n) * HID + tid] = v;
    }
}

// ---------------- GRU input GEMM (split-K) ----------------
__global__ void k_gi_init(const float* __restrict__ b_ih, float* __restrict__ gi) {
    int idx = blockIdx.x * 256 + threadIdx.x;
    if (idx < GG * GOUT) gi[idx] = b_ih[idx % GOUT];
}

__global__ __launch_bounds__(256) void k_gi_gemm(const float* __restrict__ x, const float* __restrict__ W_ih,
                                                 float* __restrict__ gi) {
    __shared__ float xs[64 * 33];
    __shared__ float wsm[192 * 33];
    int k0 = blockIdx.x * 512;
    int tid = threadIdx.x;
    int tx = tid & 15, ty = tid >> 4;
    float acc[4][12] = {};
    for (int kt = 0; kt < 16; kt++) {
        int kb = k0 + kt * 32;
        for (int idx = tid; idx < 64 * 32; idx += 256) {
            int r = idx >> 5, kk = idx & 31;
            xs[r * 33 + kk] = x[r * KGI + kb + kk];
        }
        for (int idx = tid; idx < 192 * 32; idx += 256) {
            int j = idx >> 5, kk = idx & 31;
            wsm[j * 33 + kk] = W_ih[j * KGI + kb + kk];
        }
        __syncthreads();
        for (int kk = 0; kk < 32; kk++) {
            float xv[4];
            #pragma unroll
            for (int i = 0; i < 4; i++) xv[i] = xs[(ty * 4 + i) * 33 + kk];
            #pragma unroll
            for (int jj = 0; jj < 12; jj++) {
                float wv = wsm[(tx + 16 * jj) * 33 + kk];
                #pragma unroll
                for (int i = 0; i < 4; i++) acc[i][jj] += xv[i] * wv;
            }
        }
        __syncthreads();
    }
    #pragma unroll
    for (int i = 0; i < 4; i++)
        #pragma unroll
        for (int jj = 0; jj < 12; jj++)
            atomicAdd(&gi[(ty * 4 + i) * GOUT + tx + 16 * jj], acc[i][jj]);
}

// ---------------- GRU scan (single block) ----------------
__global__ __launch_bounds__(256) void k_gru(const float* __restrict__ gi, const float* __restrict__ W_hh,
                                             const float* __restrict__ b_hh, float* __restrict__ hT) {
    __shared__ float Wt[64 * 192];   // [c][j] transposed
    __shared__ float hs[4][64];
    __shared__ float gh[4][192];
    int tid = threadIdx.x;
    for (int idx = tid; idx < 192 * 64; idx += 256) {
        int j = idx >> 6, c = idx & 63;
        Wt[c * 192 + j] = W_hh[idx];
    }
    int b_ = tid >> 6, c_ = tid & 63;
    hs[b_][c_] = 0.f;
    __syncthreads();
    for (int t = 0; t < TT; t++) {
        #pragma unroll
        for (int q = 0; q < 3; q++) {
            int p = tid + 256 * q;
            int bb = p / GOUT, j = p % GOUT;
            float a = b_hh[j];
            for (int c = 0; c < 64; c++) a += hs[bb][c] * Wt[c * 192 + j];
            gh[bb][j] = a;
        }
        __syncthreads();
        int row = (b_ * TT + t) * GOUT;
        float ir = gi[row + c_], iz = gi[row + 64 + c_], in_ = gi[row + 128 + c_];
        float r = 1.f / (1.f + expf(-(ir + gh[b_][c_])));
        float z = 1.f / (1.f + expf(-(iz + gh[b_][64 + c_])));
        float nv = tanhf(in_ + r * gh[b_][128 + c_]);
        float hn = (1.f - z) * nv + z * hs[b_][c_];
        hs[b_][c_] = hn;
        __syncthreads();
    }
    hT[tid] = hs[b_][c_];
}

// ---------------- final FC ----------------
__global__ void k_final(const float* __restrict__ hT, const float* __restrict__ W_fc,
                        const float* __restrict__ b_fc, float* __restrict__ out) {
    int idx = blockIdx.x * 256 + threadIdx.x;
    if (idx >= NB * NNODE) return;
    int b = idx / NNODE, n = idx % NNODE;
    float acc = b_fc[n];
    #pragma unroll
    for (int c = 0; c < HID; c++) acc += hT[b * HID + c] * W_fc[c * NNODE + n];
    out[idx] = acc;
}

extern "C" void kernel_launch(void* const* d_in, const int* in_sizes, int n_in,
                              void* d_out, int out_size, void* d_ws, size_t ws_size,
                              hipStream_t stream) {
    const float* x_seq  = (const float*)d_in[0];
    const int*   eidx   = (const int*)  d_in[1];
    // d_in[2] edge_weight: unused by GATConv
    const float* W_in   = (const float*)d_in[3];
    const float* b_in   = (const float*)d_in[4];
    const float* Wg     = (const float*)d_in[5];
    const float* a_src  = (const float*)d_in[6];
    const float* a_dst  = (const float*)d_in[7];
    const float* bg     = (const float*)d_in[8];
    const float* W_ih   = (const float*)d_in[9];
    const float* W_hh   = (const float*)d_in[10];
    const float* b_ih   = (const float*)d_in[11];
    const float* b_hh   = (const float*)d_in[12];
    const float* W_fc   = (const float*)d_in[13];
    const float* b_fc   = (const float*)d_in[14];
    float* out = (float*)d_out;

    float* wsf = (float*)d_ws;
    size_t off = 0;
    float* x0   = wsf + off; off += (size_t)ROWS * HID;    // 4,096,000
    float* x1   = wsf + off; off += (size_t)ROWS * HID;    // 4,096,000
    float* hbuf = wsf + off; off += (size_t)ROWS * HCOL;   // 16,384,000
    float* lsb  = wsf + off; off += (size_t)ROWS * HEADS;  // 256,000
    float* ldb  = wsf + off; off += (size_t)ROWS * HEADS;  // 256,000
    float* gib  = wsf + off; off += GG * GOUT;             // 12,288
    float* hTb  = wsf + off; off += 256;
    int* ib = (int*)(wsf + off);
    int* src_e  = ib;            ib += EP;
    int* dst_e  = ib;            ib += EP;
    int* rowptr = ib;            ib += NNODE + 1;
    int* colidx = ib;            ib += EP;
    int* deg    = ib;            ib += NNODE;
    int* fill   = ib;            ib += NNODE;

    k_build_edges<<<(EP + 255) / 256, 256, 0, stream>>>(eidx, src_e, dst_e, deg, fill);
    k_csr_count<<<(EP + 255) / 256, 256, 0, stream>>>(dst_e, deg);
    k_csr_scan<<<1, 64, 0, stream>>>(deg, rowptr);
    k_csr_fill<<<(EP + 255) / 256, 256, 0, stream>>>(dst_e, rowptr, fill, colidx);

    k_input_fc<<<ROWS * HID / 256, 256, 0, stream>>>(x_seq, W_in, b_in, x0);

    const float* xcur = x0;
    float* xnext = x1;
    for (int l = 0; l < NL; l++) {
        k_gat_h<<<dim3(ROWS / 64, HEADS), 256, 0, stream>>>(
            xcur, Wg + (size_t)l * HID * HCOL, a_src + (size_t)l * HEADS * HID,
            a_dst + (size_t)l * HEADS * HID, hbuf, lsb, ldb);
        k_gat_agg<<<dim3(NNODE, GG), 256, 0, stream>>>(
            hbuf, lsb, ldb, rowptr, colidx, src_e, bg + (size_t)l * HID, xnext);
        const float* tmp = xcur; xcur = xnext; xnext = (float*)tmp;
    }

    k_gi_init<<<(GG * GOUT + 255) / 256, 256, 0, stream>>>(b_ih, gib);
    k_gi_gemm<<<KGI / 512, 256, 0, stream>>>(xcur, W_ih, gib);
    k_gru<<<1, 256, 0, stream>>>(gib, W_hh, b_hh, hTb);
    k_final<<<(NB * NNODE + 255) / 256, 256, 0, stream>>>(hTb, W_fc, b_fc, out);
}

// Round 2
// 1094.007 us; speedup vs baseline: 1.3986x; 1.3986x over previous
//
#include <hip/hip_runtime.h>
#include <math.h>

#define NB 4
#define TT 16
#define NNODE 1000
#define FIN 8
#define EE 8000
#define EP 9000          // E + N self loops
#define HID 64
#define HEADS 4
#define NL 5
#define GG (NB*TT)       // 64 graphs
#define ROWS (GG*NNODE)  // 64000
#define HCOL (HEADS*HID) // 256
#define KGI (NNODE*HID)  // 64000
#define GOUT 192         // 3*HID

// ---------------- edge prep ----------------
__global__ void k_build_edges(const int* __restrict__ eidx, int* __restrict__ src_e,
                              int* __restrict__ dst_e, int* __restrict__ deg, int* __restrict__ fill) {
    int i = blockIdx.x * blockDim.x + threadIdx.x;
    if (i < EP) {
        int s, d;
        if (i < EE) { s = eidx[i]; d = eidx[EE + i]; }
        else { s = i - EE; d = i - EE; }
        src_e[i] = s; dst_e[i] = d;
    }
    if (i < NNODE) { deg[i] = 0; fill[i] = 0; }
}

__global__ void k_csr_count(const int* __restrict__ dst_e, int* __restrict__ deg) {
    int i = blockIdx.x * blockDim.x + threadIdx.x;
    if (i < EP) atomicAdd(&deg[dst_e[i]], 1);
}

// parallel inclusive scan over 1024 (padded) in LDS
__global__ __launch_bounds__(256) void k_csr_scan(const int* __restrict__ deg, int* __restrict__ rowptr) {
    __shared__ int s[1024];
    int tid = threadIdx.x;
    for (int i = tid; i < 1024; i += 256) s[i] = (i < NNODE) ? deg[i] : 0;
    __syncthreads();
    for (int off = 1; off < 1024; off <<= 1) {
        int t[4];
        #pragma unroll
        for (int q = 0; q < 4; q++) { int i = tid + 256 * q; t[q] = (i >= off) ? s[i - off] : 0; }
        __syncthreads();
        #pragma unroll
        for (int q = 0; q < 4; q++) { int i = tid + 256 * q; s[i] += t[q]; }
        __syncthreads();
    }
    for (int i = tid; i < NNODE; i += 256) rowptr[i + 1] = s[i];
    if (tid == 0) rowptr[0] = 0;
}

__global__ void k_csr_fill(const int* __restrict__ src_e, const int* __restrict__ dst_e,
                           const int* __restrict__ rowptr, int* __restrict__ fill,
                           int* __restrict__ csr_src, int* __restrict__ csr_dst) {
    int i = blockIdx.x * blockDim.x + threadIdx.x;
    if (i < EP) {
        int d = dst_e[i];
        int pos = atomicAdd(&fill[d], 1);
        int slot = rowptr[d] + pos;
        csr_src[slot] = src_e[i];
        csr_dst[slot] = d;
    }
}

// ---------------- input projection ----------------
__global__ void k_input_fc(const float* __restrict__ xseq, const float* __restrict__ W_in,
                           const float* __restrict__ b_in, float* __restrict__ x0) {
    int idx = blockIdx.x * 256 + threadIdx.x;   // ROWS*HID threads
    int r = idx >> 6, c = idx & 63;
    float acc = b_in[c];
    #pragma unroll
    for (int k = 0; k < FIN; k++) acc += xseq[r * FIN + k] * W_in[k * HID + c];
    x0[idx] = acc;
}

// ---------------- GAT: h = x @ W, plus ls/ld attention dots ----------------
__global__ __launch_bounds__(256) void k_gat_h(const float* __restrict__ x, const float* __restrict__ W,
                                               const float* __restrict__ asrc, const float* __restrict__ adst,
                                               float* __restrict__ h, float* __restrict__ ls, float* __restrict__ ld) {
    __shared__ float xs[64 * 65];                 // [node][k], padded
    __shared__ __align__(16) float ws[64 * 64];   // [k][c]
    int r0 = blockIdx.x * 64;
    int head = blockIdx.y;
    int c0 = head * 64;
    int tid = threadIdx.x;
    for (int idx = tid; idx < 4096; idx += 256) {
        int a = idx >> 6, b = idx & 63;
        xs[a * 65 + b] = x[(r0 + a) * HID + b];
        ws[idx] = W[a * HCOL + c0 + b];
    }
    __syncthreads();
    int tx = tid & 15, ty = tid >> 4;
    float acc[4][4] = {};
    for (int k = 0; k < 64; k++) {
        float4 w4 = *reinterpret_cast<const float4*>(&ws[k * 64 + tx * 4]);
        #pragma unroll
        for (int i = 0; i < 4; i++) {
            float xv = xs[(ty * 4 + i) * 65 + k];
            acc[i][0] += xv * w4.x;
            acc[i][1] += xv * w4.y;
            acc[i][2] += xv * w4.z;
            acc[i][3] += xv * w4.w;
        }
    }
    #pragma unroll
    for (int i = 0; i < 4; i++) {
        float4 v = make_float4(acc[i][0], acc[i][1], acc[i][2], acc[i][3]);
        *reinterpret_cast<float4*>(&h[(r0 + ty * 4 + i) * HCOL + c0 + tx * 4]) = v;
    }
    float a0 = asrc[c0 + tx * 4 + 0], a1 = asrc[c0 + tx * 4 + 1];
    float a2 = asrc[c0 + tx * 4 + 2], a3 = asrc[c0 + tx * 4 + 3];
    float d0 = adst[c0 + tx * 4 + 0], d1 = adst[c0 + tx * 4 + 1];
    float d2 = adst[c0 + tx * 4 + 2], d3 = adst[c0 + tx * 4 + 3];
    #pragma unroll
    for (int i = 0; i < 4; i++) {
        float ps = acc[i][0] * a0 + acc[i][1] * a1 + acc[i][2] * a2 + acc[i][3] * a3;
        float pd = acc[i][0] * d0 + acc[i][1] * d1 + acc[i][2] * d2 + acc[i][3] * d3;
        #pragma unroll
        for (int m = 1; m < 16; m <<= 1) {
            ps += __shfl_xor(ps, m, 64);
            pd += __shfl_xor(pd, m, 64);
        }
        if (tx == 0) {
            ls[(r0 + ty * 4 + i) * HEADS + head] = ps;
            ld[(r0 + ty * 4 + i) * HEADS + head] = pd;
        }
    }
}

// ---------------- edge-parallel attention logits ----------------
__global__ void k_logit(const float* __restrict__ ls, const float* __restrict__ ld,
                        const int* __restrict__ csr_src, const int* __restrict__ csr_dst,
                        float* __restrict__ ealpha) {
    int idx = blockIdx.x * 256 + threadIdx.x;     // GG*EP*HEADS
    int hd = idx & 3;
    int t = idx >> 2;
    int slot = t % EP, g = t / EP;
    int s = csr_src[slot], d = csr_dst[slot];
    float v = ls[(g * NNODE + s) * HEADS + hd] + ld[(g * NNODE + d) * HEADS + hd];
    v = v >= 0.f ? v : 0.2f * v;
    ealpha[idx] = v;
}

// ---------------- per-(g,n,h) softmax max/denominator ----------------
__global__ void k_softmax(const float* __restrict__ ealpha, const int* __restrict__ rowptr,
                          float2* __restrict__ mden) {
    int idx = blockIdx.x * 256 + threadIdx.x;     // GG*NNODE*HEADS
    int hd = idx & 3;
    int t = idx >> 2;
    int n = t % NNODE, g = t / NNODE;
    int rs = rowptr[n], re = rowptr[n + 1];
    const float* base = ealpha + (size_t)g * EP * HEADS + hd;
    float m = -INFINITY;
    for (int j = rs; j < re; j++) m = fmaxf(m, base[j * HEADS]);
    float den = 0.f;
    for (int j = rs; j < re; j++) den += expf(base[j * HEADS] - m);
    mden[idx] = make_float2(m, 1.f / (den + 1e-16f));
}

// ---------------- GAT aggregate (+ mean heads + bias + ELU) ----------------
__global__ __launch_bounds__(256) void k_gat_agg2(const float* __restrict__ h, const float* __restrict__ ealpha,
                                                  const float2* __restrict__ mden, const int* __restrict__ rowptr,
                                                  const int* __restrict__ csr_src, const float* __restrict__ bg,
                                                  float* __restrict__ xout) {
    int b = blockIdx.x;
    // XCD swizzle: keep all nodes of one graph on one XCD (dispatch assumed round-robin)
    int xcd = b & 7, slot = b >> 3;
    int g = xcd + 8 * (slot / NNODE);
    int n = slot % NNODE;
    int tid = threadIdx.x;
    int hd = tid >> 6, lane = tid & 63;
    int rs = rowptr[n], re = rowptr[n + 1];
    float2 md = mden[(g * NNODE + n) * HEADS + hd];
    const float* ea = ealpha + (size_t)g * EP * HEADS + hd;
    float acc = 0.f;
    for (int bb = rs; bb < re; bb += 64) {
        int myidx = bb + lane;
        float myalpha = 0.f; int mysrc = 0;
        if (myidx < re) {
            mysrc = csr_src[myidx];
            myalpha = expf(ea[(size_t)myidx * HEADS] - md.x) * md.y;
        }
        int cnt = min(64, re - bb);
        for (int j = 0; j < cnt; j++) {
            float a = __shfl(myalpha, j, 64);
            int s = __shfl(mysrc, j, 64);
            acc += a * h[(size_t)(g * NNODE + s) * HCOL + hd * HID + lane];
        }
    }
    __shared__ float agg[4][64];
    agg[hd][lane] = acc;
    __syncthreads();
    if (tid < 64) {
        float v = (agg[0][tid] + agg[1][tid] + agg[2][tid] + agg[3][tid]) * 0.25f + bg[tid];
        v = v > 0.f ? v : expm1f(v);
        xout[(g * NNODE + n) * HID + tid] = v;
    }
}

// ---------------- GRU input GEMM (split-K) ----------------
__global__ void k_gi_init(const float* __restrict__ b_ih, float* __restrict__ gi) {
    int idx = blockIdx.x * 256 + threadIdx.x;
    if (idx < GG * GOUT) gi[idx] = b_ih[idx % GOUT];
}

__global__ __launch_bounds__(256) void k_gi_gemm(const float* __restrict__ x, const float* __restrict__ W_ih,
                                                 float* __restrict__ gi) {
    __shared__ float xs[64 * 33];
    __shared__ float wsm[192 * 33];
    int k0 = blockIdx.x * 256;   // 250 blocks x 256-K slices
    int tid = threadIdx.x;
    int tx = tid & 15, ty = tid >> 4;
    float acc[4][12] = {};
    for (int kt = 0; kt < 8; kt++) {
        int kb = k0 + kt * 32;
        for (int idx = tid; idx < 64 * 32; idx += 256) {
            int r = idx >> 5, kk = idx & 31;
            xs[r * 33 + kk] = x[r * KGI + kb + kk];
        }
        for (int idx = tid; idx < 192 * 32; idx += 256) {
            int j = idx >> 5, kk = idx & 31;
            wsm[j * 33 + kk] = W_ih[(size_t)j * KGI + kb + kk];
        }
        __syncthreads();
        for (int kk = 0; kk < 32; kk++) {
            float xv[4];
            #pragma unroll
            for (int i = 0; i < 4; i++) xv[i] = xs[(ty * 4 + i) * 33 + kk];
            #pragma unroll
            for (int jj = 0; jj < 12; jj++) {
                float wv = wsm[(tx + 16 * jj) * 33 + kk];
                #pragma unroll
                for (int i = 0; i < 4; i++) acc[i][jj] += xv[i] * wv;
            }
        }
        __syncthreads();
    }
    #pragma unroll
    for (int i = 0; i < 4; i++)
        #pragma unroll
        for (int jj = 0; jj < 12; jj++)
            atomicAdd(&gi[(ty * 4 + i) * GOUT + tx + 16 * jj], acc[i][jj]);
}

// ---------------- GRU scan (single block) ----------------
__global__ __launch_bounds__(256) void k_gru(const float* __restrict__ gi, const float* __restrict__ W_hh,
                                             const float* __restrict__ b_hh, float* __restrict__ hT) {
    __shared__ float Wt[64 * 192];   // [c][j] transposed
    __shared__ float hs[4][64];
    __shared__ float gh[4][192];
    int tid = threadIdx.x;
    for (int idx = tid; idx < 192 * 64; idx += 256) {
        int j = idx >> 6, c = idx & 63;
        Wt[c * 192 + j] = W_hh[idx];
    }
    int b_ = tid >> 6, c_ = tid & 63;
    hs[b_][c_] = 0.f;
    __syncthreads();
    for (int t = 0; t < TT; t++) {
        #pragma unroll
        for (int q = 0; q < 3; q++) {
            int p = tid + 256 * q;
            int bb = p / GOUT, j = p % GOUT;
            float a = b_hh[j];
            for (int c = 0; c < 64; c++) a += hs[bb][c] * Wt[c * 192 + j];
            gh[bb][j] = a;
        }
        __syncthreads();
        int row = (b_ * TT + t) * GOUT;
        float ir = gi[row + c_], iz = gi[row + 64 + c_], in_ = gi[row + 128 + c_];
        float r = 1.f / (1.f + expf(-(ir + gh[b_][c_])));
        float z = 1.f / (1.f + expf(-(iz + gh[b_][64 + c_])));
        float nv = tanhf(in_ + r * gh[b_][128 + c_]);
        float hn = (1.f - z) * nv + z * hs[b_][c_];
        hs[b_][c_] = hn;
        __syncthreads();
    }
    hT[tid] = hs[b_][c_];
}

// ---------------- final FC ----------------
__global__ void k_final(const float* __restrict__ hT, const float* __restrict__ W_fc,
                        const float* __restrict__ b_fc, float* __restrict__ out) {
    int idx = blockIdx.x * 256 + threadIdx.x;
    if (idx >= NB * NNODE) return;
    int b = idx / NNODE, n = idx % NNODE;
    float acc = b_fc[n];
    #pragma unroll
    for (int c = 0; c < HID; c++) acc += hT[b * HID + c] * W_fc[c * NNODE + n];
    out[idx] = acc;
}

extern "C" void kernel_launch(void* const* d_in, const int* in_sizes, int n_in,
                              void* d_out, int out_size, void* d_ws, size_t ws_size,
                              hipStream_t stream) {
    const float* x_seq  = (const float*)d_in[0];
    const int*   eidx   = (const int*)  d_in[1];
    // d_in[2] edge_weight: unused by GATConv
    const float* W_in   = (const float*)d_in[3];
    const float* b_in   = (const float*)d_in[4];
    const float* Wg     = (const float*)d_in[5];
    const float* a_src  = (const float*)d_in[6];
    const float* a_dst  = (const float*)d_in[7];
    const float* bg     = (const float*)d_in[8];
    const float* W_ih   = (const float*)d_in[9];
    const float* W_hh   = (const float*)d_in[10];
    const float* b_ih   = (const float*)d_in[11];
    const float* b_hh   = (const float*)d_in[12];
    const float* W_fc   = (const float*)d_in[13];
    const float* b_fc   = (const float*)d_in[14];
    float* out = (float*)d_out;

    float* wsf = (float*)d_ws;
    size_t off = 0;
    float* x0     = wsf + off; off += (size_t)ROWS * HID;    // 4,096,000
    float* x1     = wsf + off; off += (size_t)ROWS * HID;    // 4,096,000
    float* hbuf   = wsf + off; off += (size_t)ROWS * HCOL;   // 16,384,000
    float* lsb    = wsf + off; off += (size_t)ROWS * HEADS;  // 256,000
    float* ldb    = wsf + off; off += (size_t)ROWS * HEADS;  // 256,000
    float* ealpha = wsf + off; off += (size_t)GG * EP * HEADS; // 2,304,000
    float2* mden  = (float2*)(wsf + off); off += (size_t)GG * NNODE * HEADS * 2; // 512,000
    float* gib    = wsf + off; off += GG * GOUT;             // 12,288
    float* hTb    = wsf + off; off += 256;
    int* ib = (int*)(wsf + off);
    int* src_e   = ib;           ib += EP;
    int* dst_e   = ib;           ib += EP;
    int* rowptr  = ib;           ib += NNODE + 1;
    int* csr_src = ib;           ib += EP;
    int* csr_dst = ib;           ib += EP;
    int* deg     = ib;           ib += NNODE;
    int* fill    = ib;           ib += NNODE;

    k_build_edges<<<(EP + 255) / 256, 256, 0, stream>>>(eidx, src_e, dst_e, deg, fill);
    k_csr_count<<<(EP + 255) / 256, 256, 0, stream>>>(dst_e, deg);
    k_csr_scan<<<1, 256, 0, stream>>>(deg, rowptr);
    k_csr_fill<<<(EP + 255) / 256, 256, 0, stream>>>(src_e, dst_e, rowptr, fill, csr_src, csr_dst);

    k_input_fc<<<ROWS * HID / 256, 256, 0, stream>>>(x_seq, W_in, b_in, x0);

    const float* xcur = x0;
    float* xnext = x1;
    for (int l = 0; l < NL; l++) {
        k_gat_h<<<dim3(ROWS / 64, HEADS), 256, 0, stream>>>(
            xcur, Wg + (size_t)l * HID * HCOL, a_src + (size_t)l * HEADS * HID,
            a_dst + (size_t)l * HEADS * HID, hbuf, lsb, ldb);
        k_logit<<<GG * EP * HEADS / 256, 256, 0, stream>>>(lsb, ldb, csr_src, csr_dst, ealpha);
        k_softmax<<<GG * NNODE * HEADS / 256, 256, 0, stream>>>(ealpha, rowptr, mden);
        k_gat_agg2<<<ROWS, 256, 0, stream>>>(hbuf, ealpha, mden, rowptr, csr_src,
                                             bg + (size_t)l * HID, xnext);
        const float* tmp = xcur; xcur = xnext; xnext = (float*)tmp;
    }

    k_gi_init<<<(GG * GOUT + 255) / 256, 256, 0, stream>>>(b_ih, gib);
    k_gi_gemm<<<KGI / 256, 256, 0, stream>>>(xcur, W_ih, gib);
    k_gru<<<1, 256, 0, stream>>>(gib, W_hh, b_hh, hTb);
    k_final<<<(NB * NNODE + 255) / 256, 256, 0, stream>>>(hTb, W_fc, b_fc, out);
}

// Round 3
// 953.579 us; speedup vs baseline: 1.6046x; 1.1473x over previous
//
#include <hip/hip_runtime.h>
#include <math.h>

#define NB 4
#define TT 16
#define NNODE 1000
#define FIN 8
#define EE 8000
#define EP 9000          // E + N self loops
#define HID 64
#define HEADS 4
#define NL 5
#define GG (NB*TT)       // 64 graphs
#define ROWS (GG*NNODE)  // 64000
#define HCOL (HEADS*HID) // 256
#define KGI (NNODE*HID)  // 64000
#define GOUT 192         // 3*HID

// ---------------- edge prep ----------------
__global__ void k_build_edges(const int* __restrict__ eidx, int* __restrict__ src_e,
                              int* __restrict__ dst_e, int* __restrict__ deg, int* __restrict__ fill) {
    int i = blockIdx.x * blockDim.x + threadIdx.x;
    if (i < EP) {
        int s, d;
        if (i < EE) { s = eidx[i]; d = eidx[EE + i]; }
        else { s = i - EE; d = i - EE; }
        src_e[i] = s; dst_e[i] = d;
    }
    if (i < NNODE) { deg[i] = 0; fill[i] = 0; }
}

__global__ void k_csr_count(const int* __restrict__ dst_e, int* __restrict__ deg) {
    int i = blockIdx.x * blockDim.x + threadIdx.x;
    if (i < EP) atomicAdd(&deg[dst_e[i]], 1);
}

// parallel inclusive scan over 1024 (padded) in LDS
__global__ __launch_bounds__(256) void k_csr_scan(const int* __restrict__ deg, int* __restrict__ rowptr) {
    __shared__ int s[1024];
    int tid = threadIdx.x;
    for (int i = tid; i < 1024; i += 256) s[i] = (i < NNODE) ? deg[i] : 0;
    __syncthreads();
    for (int off = 1; off < 1024; off <<= 1) {
        int t[4];
        #pragma unroll
        for (int q = 0; q < 4; q++) { int i = tid + 256 * q; t[q] = (i >= off) ? s[i - off] : 0; }
        __syncthreads();
        #pragma unroll
        for (int q = 0; q < 4; q++) { int i = tid + 256 * q; s[i] += t[q]; }
        __syncthreads();
    }
    for (int i = tid; i < NNODE; i += 256) rowptr[i + 1] = s[i];
    if (tid == 0) rowptr[0] = 0;
}

__global__ void k_csr_fill(const int* __restrict__ src_e, const int* __restrict__ dst_e,
                           const int* __restrict__ rowptr, int* __restrict__ fill,
                           int* __restrict__ csr_src) {
    int i = blockIdx.x * blockDim.x + threadIdx.x;
    if (i < EP) {
        int d = dst_e[i];
        int pos = atomicAdd(&fill[d], 1);
        csr_src[rowptr[d] + pos] = src_e[i];
    }
}

// ---------------- input projection (float4 over columns) ----------------
__global__ void k_input_fc(const float* __restrict__ xseq, const float4* __restrict__ Win4,
                           const float4* __restrict__ b_in4, float4* __restrict__ x0) {
    int idx = blockIdx.x * 256 + threadIdx.x;   // ROWS*16 threads
    int r = idx >> 4, c4 = idx & 15;
    float4 acc = b_in4[c4];
    #pragma unroll
    for (int k = 0; k < FIN; k++) {
        float xv = xseq[r * FIN + k];
        float4 w = Win4[k * 16 + c4];
        acc.x += xv * w.x; acc.y += xv * w.y; acc.z += xv * w.z; acc.w += xv * w.w;
    }
    x0[idx] = acc;
}

// ---------------- GAT: h = x @ W, plus ls/ld attention dots ----------------
__global__ __launch_bounds__(256) void k_gat_h(const float4* __restrict__ x4, const float4* __restrict__ W4,
                                               const float* __restrict__ asrc, const float* __restrict__ adst,
                                               float* __restrict__ h, float* __restrict__ ls, float* __restrict__ ld) {
    __shared__ float xs[64 * 65];                 // [node][k], padded
    __shared__ __align__(16) float ws[64 * 64];   // [k][c]
    int r0 = blockIdx.x * 64;
    int head = blockIdx.y;
    int c0 = head * 64;
    int tid = threadIdx.x;
    for (int idx = tid; idx < 1024; idx += 256) {
        int a = idx >> 4, kq = idx & 15;
        float4 v = x4[(size_t)(r0 + a) * 16 + kq];
        int k = kq * 4;
        xs[a * 65 + k] = v.x; xs[a * 65 + k + 1] = v.y;
        xs[a * 65 + k + 2] = v.z; xs[a * 65 + k + 3] = v.w;
    }
    for (int idx = tid; idx < 1024; idx += 256) {
        int k = idx >> 4, j = idx & 15;
        *reinterpret_cast<float4*>(&ws[k * 64 + j * 4]) = W4[(size_t)k * 64 + head * 16 + j];
    }
    __syncthreads();
    int tx = tid & 15, ty = tid >> 4;
    float acc[4][4] = {};
    for (int k = 0; k < 64; k++) {
        float4 w4 = *reinterpret_cast<const float4*>(&ws[k * 64 + tx * 4]);
        #pragma unroll
        for (int i = 0; i < 4; i++) {
            float xv = xs[(ty * 4 + i) * 65 + k];
            acc[i][0] += xv * w4.x;
            acc[i][1] += xv * w4.y;
            acc[i][2] += xv * w4.z;
            acc[i][3] += xv * w4.w;
        }
    }
    #pragma unroll
    for (int i = 0; i < 4; i++) {
        float4 v = make_float4(acc[i][0], acc[i][1], acc[i][2], acc[i][3]);
        *reinterpret_cast<float4*>(&h[(size_t)(r0 + ty * 4 + i) * HCOL + c0 + tx * 4]) = v;
    }
    float a0 = asrc[c0 + tx * 4 + 0], a1 = asrc[c0 + tx * 4 + 1];
    float a2 = asrc[c0 + tx * 4 + 2], a3 = asrc[c0 + tx * 4 + 3];
    float d0 = adst[c0 + tx * 4 + 0], d1 = adst[c0 + tx * 4 + 1];
    float d2 = adst[c0 + tx * 4 + 2], d3 = adst[c0 + tx * 4 + 3];
    #pragma unroll
    for (int i = 0; i < 4; i++) {
        float ps = acc[i][0] * a0 + acc[i][1] * a1 + acc[i][2] * a2 + acc[i][3] * a3;
        float pd = acc[i][0] * d0 + acc[i][1] * d1 + acc[i][2] * d2 + acc[i][3] * d3;
        #pragma unroll
        for (int m = 1; m < 16; m <<= 1) {
            ps += __shfl_xor(ps, m, 64);
            pd += __shfl_xor(pd, m, 64);
        }
        if (tx == 0) {
            ls[(size_t)(r0 + ty * 4 + i) * HEADS + head] = ps;
            ld[(size_t)(r0 + ty * 4 + i) * HEADS + head] = pd;
        }
    }
}

// ---------------- fused logits + softmax + alpha, per (g,n), 4 heads as float4 ----------------
__global__ __launch_bounds__(256) void k_alpha(const float4* __restrict__ ls4, const float4* __restrict__ ld4,
                                               const int* __restrict__ rowptr, const int* __restrict__ csr_src,
                                               float4* __restrict__ abuf) {
    int idx = blockIdx.x * 256 + threadIdx.x;     // GG*NNODE
    if (idx >= GG * NNODE) return;
    int g = idx / NNODE, n = idx - g * NNODE;
    int rs = rowptr[n], re = rowptr[n + 1];
    int dg = re - rs;
    float4 ldv = ld4[(size_t)g * NNODE + n];
    const float4* lsg = ls4 + (size_t)g * NNODE;
    float4* out = abuf + (size_t)g * EP;
    if (dg <= 16) {
        int sv[16];
        float4 v[16];
        #pragma unroll
        for (int u = 0; u < 16; u++) sv[u] = (u < dg) ? csr_src[rs + u] : 0;
        #pragma unroll
        for (int u = 0; u < 16; u++) {
            if (u < dg) {
                float4 t = lsg[sv[u]];
                t.x += ldv.x; t.y += ldv.y; t.z += ldv.z; t.w += ldv.w;
                t.x = t.x >= 0.f ? t.x : 0.2f * t.x;
                t.y = t.y >= 0.f ? t.y : 0.2f * t.y;
                t.z = t.z >= 0.f ? t.z : 0.2f * t.z;
                t.w = t.w >= 0.f ? t.w : 0.2f * t.w;
                v[u] = t;
            }
        }
        float4 m = make_float4(-1e30f, -1e30f, -1e30f, -1e30f);
        #pragma unroll
        for (int u = 0; u < 16; u++) {
            if (u < dg) {
                m.x = fmaxf(m.x, v[u].x); m.y = fmaxf(m.y, v[u].y);
                m.z = fmaxf(m.z, v[u].z); m.w = fmaxf(m.w, v[u].w);
            }
        }
        float4 den = make_float4(0.f, 0.f, 0.f, 0.f);
        #pragma unroll
        for (int u = 0; u < 16; u++) {
            if (u < dg) {
                v[u].x = expf(v[u].x - m.x); den.x += v[u].x;
                v[u].y = expf(v[u].y - m.y); den.y += v[u].y;
                v[u].z = expf(v[u].z - m.z); den.z += v[u].z;
                v[u].w = expf(v[u].w - m.w); den.w += v[u].w;
            }
        }
        float4 inv = make_float4(1.f / (den.x + 1e-16f), 1.f / (den.y + 1e-16f),
                                 1.f / (den.z + 1e-16f), 1.f / (den.w + 1e-16f));
        #pragma unroll
        for (int u = 0; u < 16; u++) {
            if (u < dg) {
                float4 t = make_float4(v[u].x * inv.x, v[u].y * inv.y, v[u].z * inv.z, v[u].w * inv.w);
                out[rs + u] = t;
            }
        }
    } else {
        // rare general path
        float4 m = make_float4(-1e30f, -1e30f, -1e30f, -1e30f);
        for (int j = rs; j < re; j++) {
            float4 t = lsg[csr_src[j]];
            t.x += ldv.x; t.y += ldv.y; t.z += ldv.z; t.w += ldv.w;
            t.x = t.x >= 0.f ? t.x : 0.2f * t.x;
            t.y = t.y >= 0.f ? t.y : 0.2f * t.y;
            t.z = t.z >= 0.f ? t.z : 0.2f * t.z;
            t.w = t.w >= 0.f ? t.w : 0.2f * t.w;
            out[j] = t;
            m.x = fmaxf(m.x, t.x); m.y = fmaxf(m.y, t.y);
            m.z = fmaxf(m.z, t.z); m.w = fmaxf(m.w, t.w);
        }
        float4 den = make_float4(0.f, 0.f, 0.f, 0.f);
        for (int j = rs; j < re; j++) {
            float4 t = out[j];
            t.x = expf(t.x - m.x); den.x += t.x;
            t.y = expf(t.y - m.y); den.y += t.y;
            t.z = expf(t.z - m.z); den.z += t.z;
            t.w = expf(t.w - m.w); den.w += t.w;
            out[j] = t;
        }
        float4 inv = make_float4(1.f / (den.x + 1e-16f), 1.f / (den.y + 1e-16f),
                                 1.f / (den.z + 1e-16f), 1.f / (den.w + 1e-16f));
        for (int j = rs; j < re; j++) {
            float4 t = out[j];
            t.x *= inv.x; t.y *= inv.y; t.z *= inv.z; t.w *= inv.w;
            out[j] = t;
        }
    }
}

// ---------------- GAT aggregate: one wave per (g,n), lane = head*16+c4 ----------------
__global__ __launch_bounds__(256) void k_agg(const float4* __restrict__ h4, const float* __restrict__ alpha,
                                             const int* __restrict__ rowptr, const int* __restrict__ csr_src,
                                             const float4* __restrict__ bg4, float4* __restrict__ xout4) {
    __shared__ int s_lds[1024];
    int n = blockIdx.x;
    int tid = threadIdx.x;
    int wid = tid >> 6, lane = tid & 63;
    int g = blockIdx.y * 4 + wid;
    int head = lane >> 4, c4 = lane & 15;
    int rs = rowptr[n], re = rowptr[n + 1];
    int dg = re - rs;
    for (int j = tid; j < dg; j += 256) s_lds[j] = csr_src[rs + j];
    __syncthreads();
    const float* ag = alpha + ((size_t)g * EP + rs) * HEADS + head;
    const float4* hg = h4 + (size_t)g * NNODE * 64 + head * 16 + c4;
    float4 acc = make_float4(0.f, 0.f, 0.f, 0.f);
    for (int j0 = 0; j0 < dg; j0 += 16) {
        int cnt = dg - j0;
        int sv[16]; float av[16];
        #pragma unroll
        for (int u = 0; u < 16; u++) {
            bool ok = u < cnt;
            sv[u] = ok ? s_lds[j0 + u] : 0;
            av[u] = ok ? ag[(size_t)(j0 + u) * HEADS] : 0.f;
        }
        float4 hv[16];
        #pragma unroll
        for (int u = 0; u < 16; u++) hv[u] = hg[(size_t)sv[u] * 64];
        #pragma unroll
        for (int u = 0; u < 16; u++) {
            acc.x += av[u] * hv[u].x;
            acc.y += av[u] * hv[u].y;
            acc.z += av[u] * hv[u].z;
            acc.w += av[u] * hv[u].w;
        }
    }
    // mean over heads: lanes differing in bits 4,5
    #pragma unroll
    for (int m = 16; m < 64; m <<= 1) {
        acc.x += __shfl_xor(acc.x, m, 64);
        acc.y += __shfl_xor(acc.y, m, 64);
        acc.z += __shfl_xor(acc.z, m, 64);
        acc.w += __shfl_xor(acc.w, m, 64);
    }
    if (head == 0) {
        float4 b = bg4[c4];
        acc.x = acc.x * 0.25f + b.x;
        acc.y = acc.y * 0.25f + b.y;
        acc.z = acc.z * 0.25f + b.z;
        acc.w = acc.w * 0.25f + b.w;
        acc.x = acc.x > 0.f ? acc.x : expm1f(acc.x);
        acc.y = acc.y > 0.f ? acc.y : expm1f(acc.y);
        acc.z = acc.z > 0.f ? acc.z : expm1f(acc.z);
        acc.w = acc.w > 0.f ? acc.w : expm1f(acc.w);
        xout4[((size_t)g * NNODE + n) * 16 + c4] = acc;
    }
}

// ---------------- GRU input GEMM (split-K) ----------------
__global__ void k_gi_init(const float* __restrict__ b_ih, float* __restrict__ gi) {
    int idx = blockIdx.x * 256 + threadIdx.x;
    if (idx < GG * GOUT) gi[idx] = b_ih[idx % GOUT];
}

__global__ __launch_bounds__(256) void k_gi_gemm(const float* __restrict__ x, const float* __restrict__ W_ih,
                                                 float* __restrict__ gi) {
    __shared__ float xs[64 * 33];
    __shared__ float wsm[192 * 33];
    int k0 = blockIdx.x * 256;   // 250 blocks x 256-K slices
    int tid = threadIdx.x;
    int tx = tid & 15, ty = tid >> 4;
    float acc[4][12] = {};
    for (int kt = 0; kt < 8; kt++) {
        int kb = k0 + kt * 32;
        for (int idx = tid; idx < 64 * 32; idx += 256) {
            int r = idx >> 5, kk = idx & 31;
            xs[r * 33 + kk] = x[r * KGI + kb + kk];
        }
        for (int idx = tid; idx < 192 * 32; idx += 256) {
            int j = idx >> 5, kk = idx & 31;
            wsm[j * 33 + kk] = W_ih[(size_t)j * KGI + kb + kk];
        }
        __syncthreads();
        for (int kk = 0; kk < 32; kk++) {
            float xv[4];
            #pragma unroll
            for (int i = 0; i < 4; i++) xv[i] = xs[(ty * 4 + i) * 33 + kk];
            #pragma unroll
            for (int jj = 0; jj < 12; jj++) {
                float wv = wsm[(tx + 16 * jj) * 33 + kk];
                #pragma unroll
                for (int i = 0; i < 4; i++) acc[i][jj] += xv[i] * wv;
            }
        }
        __syncthreads();
    }
    #pragma unroll
    for (int i = 0; i < 4; i++)
        #pragma unroll
        for (int jj = 0; jj < 12; jj++)
            atomicAdd(&gi[(ty * 4 + i) * GOUT + tx + 16 * jj], acc[i][jj]);
}

// ---------------- GRU scan (single block) ----------------
__global__ __launch_bounds__(256) void k_gru(const float* __restrict__ gi, const float* __restrict__ W_hh,
                                             const float* __restrict__ b_hh, float* __restrict__ hT) {
    __shared__ float Wt[64 * 192];   // [c][j] transposed
    __shared__ float hs[4][64];
    __shared__ float gh[4][192];
    int tid = threadIdx.x;
    for (int idx = tid; idx < 192 * 64; idx += 256) {
        int j = idx >> 6, c = idx & 63;
        Wt[c * 192 + j] = W_hh[idx];
    }
    int b_ = tid >> 6, c_ = tid & 63;
    hs[b_][c_] = 0.f;
    __syncthreads();
    for (int t = 0; t < TT; t++) {
        #pragma unroll
        for (int q = 0; q < 3; q++) {
            int p = tid + 256 * q;
            int bb = p / GOUT, j = p % GOUT;
            float a = b_hh[j];
            for (int c = 0; c < 64; c++) a += hs[bb][c] * Wt[c * 192 + j];
            gh[bb][j] = a;
        }
        __syncthreads();
        int row = (b_ * TT + t) * GOUT;
        float ir = gi[row + c_], iz = gi[row + 64 + c_], in_ = gi[row + 128 + c_];
        float r = 1.f / (1.f + expf(-(ir + gh[b_][c_])));
        float z = 1.f / (1.f + expf(-(iz + gh[b_][64 + c_])));
        float nv = tanhf(in_ + r * gh[b_][128 + c_]);
        float hn = (1.f - z) * nv + z * hs[b_][c_];
        hs[b_][c_] = hn;
        __syncthreads();
    }
    hT[tid] = hs[b_][c_];
}

// ---------------- final FC ----------------
__global__ void k_final(const float* __restrict__ hT, const float* __restrict__ W_fc,
                        const float* __restrict__ b_fc, float* __restrict__ out) {
    int idx = blockIdx.x * 256 + threadIdx.x;
    if (idx >= NB * NNODE) return;
    int b = idx / NNODE, n = idx % NNODE;
    float acc = b_fc[n];
    #pragma unroll
    for (int c = 0; c < HID; c++) acc += hT[b * HID + c] * W_fc[c * NNODE + n];
    out[idx] = acc;
}

extern "C" void kernel_launch(void* const* d_in, const int* in_sizes, int n_in,
                              void* d_out, int out_size, void* d_ws, size_t ws_size,
                              hipStream_t stream) {
    const float* x_seq  = (const float*)d_in[0];
    const int*   eidx   = (const int*)  d_in[1];
    // d_in[2] edge_weight: unused by GATConv
    const float* W_in   = (const float*)d_in[3];
    const float* b_in   = (const float*)d_in[4];
    const float* Wg     = (const float*)d_in[5];
    const float* a_src  = (const float*)d_in[6];
    const float* a_dst  = (const float*)d_in[7];
    const float* bg     = (const float*)d_in[8];
    const float* W_ih   = (const float*)d_in[9];
    const float* W_hh   = (const float*)d_in[10];
    const float* b_ih   = (const float*)d_in[11];
    const float* b_hh   = (const float*)d_in[12];
    const float* W_fc   = (const float*)d_in[13];
    const float* b_fc   = (const float*)d_in[14];
    float* out = (float*)d_out;

    float* wsf = (float*)d_ws;
    size_t off = 0;
    float* x0     = wsf + off; off += (size_t)ROWS * HID;      // 4,096,000
    float* x1     = wsf + off; off += (size_t)ROWS * HID;      // 4,096,000
    float* hbuf   = wsf + off; off += (size_t)ROWS * HCOL;     // 16,384,000
    float* lsb    = wsf + off; off += (size_t)ROWS * HEADS;    // 256,000
    float* ldb    = wsf + off; off += (size_t)ROWS * HEADS;    // 256,000
    float* abuf   = wsf + off; off += (size_t)GG * EP * HEADS; // 2,304,000
    float* gib    = wsf + off; off += GG * GOUT;               // 12,288
    float* hTb    = wsf + off; off += 256;
    int* ib = (int*)(wsf + off);
    int* src_e   = ib;           ib += EP;
    int* dst_e   = ib;           ib += EP;
    int* rowptr  = ib;           ib += NNODE + 1;
    int* csr_src = ib;           ib += EP;
    int* deg     = ib;           ib += NNODE;
    int* fill    = ib;           ib += NNODE;

    k_build_edges<<<(EP + 255) / 256, 256, 0, stream>>>(eidx, src_e, dst_e, deg, fill);
    k_csr_count<<<(EP + 255) / 256, 256, 0, stream>>>(dst_e, deg);
    k_csr_scan<<<1, 256, 0, stream>>>(deg, rowptr);
    k_csr_fill<<<(EP + 255) / 256, 256, 0, stream>>>(src_e, dst_e, rowptr, fill, csr_src);

    k_input_fc<<<ROWS * 16 / 256, 256, 0, stream>>>(x_seq, (const float4*)W_in, (const float4*)b_in,
                                                    (float4*)x0);

    const float* xcur = x0;
    float* xnext = x1;
    for (int l = 0; l < NL; l++) {
        k_gat_h<<<dim3(ROWS / 64, HEADS), 256, 0, stream>>>(
            (const float4*)xcur, (const float4*)(Wg + (size_t)l * HID * HCOL),
            a_src + (size_t)l * HEADS * HID, a_dst + (size_t)l * HEADS * HID, hbuf, lsb, ldb);
        k_alpha<<<(GG * NNODE + 255) / 256, 256, 0, stream>>>(
            (const float4*)lsb, (const float4*)ldb, rowptr, csr_src, (float4*)abuf);
        k_agg<<<dim3(NNODE, GG / 4), 256, 0, stream>>>(
            (const float4*)hbuf, abuf, rowptr, csr_src,
            (const float4*)(bg + (size_t)l * HID), (float4*)xnext);
        const float* tmp = xcur; xcur = xnext; xnext = (float*)tmp;
    }

    k_gi_init<<<(GG * GOUT + 255) / 256, 256, 0, stream>>>(b_ih, gib);
    k_gi_gemm<<<KGI / 256, 256, 0, stream>>>(xcur, W_ih, gib);
    k_gru<<<1, 256, 0, stream>>>(gib, W_hh, b_hh, hTb);
    k_final<<<(NB * NNODE + 255) / 256, 256, 0, stream>>>(hTb, W_fc, b_fc, out);
}